// Round 8
// baseline (200.553 us; speedup 1.0000x reference)
//
#include <hip/hip_runtime.h>
#include <hip/hip_fp16.h>

#define N_NODES 50000
#define N_EDGES 800000
#define BSHIFT 8
#define NBKT ((N_NODES + 255) >> BSHIFT)                 // 196 buckets of 256 nodes
#define P1_EDGES 4096
#define P1_BLOCKS ((N_EDGES + P1_EDGES - 1) / P1_EDGES)  // 196
#define NSEG 4
#define SEG_LEN ((P1_BLOCKS + NSEG - 1) / NSEG)          // 49
#define SORT_LDS_CAP 5000                                 // 40 KB; bucket mean 4082, sigma 64

// ===== Pass 0: per-block bucket counts -> cnt[blk][bucket] =====
__global__ void count_kernel(const int* __restrict__ dst, int* __restrict__ cnt) {
    __shared__ int h[NBKT];
    int t = threadIdx.x;
    if (t < NBKT) h[t] = 0;
    __syncthreads();
    int e0 = blockIdx.x * P1_EDGES;
    for (int k = 0; k < P1_EDGES / 256; k++) {
        int e = e0 + k * 256 + t;
        if (e < N_EDGES) atomicAdd(&h[dst[e] >> BSHIFT], 1);
    }
    __syncthreads();
    if (t < NBKT) cnt[blockIdx.x * NBKT + t] = h[t];
}

// ===== Pass 0.5: cnt -> exact per-(block,bucket) cursors; bucket bases. 4-way segmented. =====
__global__ void scan_matrix(int* __restrict__ cnt, int* __restrict__ bbase) {
    __shared__ int segsum[NSEG][256];
    __shared__ int btot[256];
    int t = threadIdx.x & 255;   // bucket
    int s = threadIdx.x >> 8;    // segment
    int sum = 0;
    if (t < NBKT) {
        for (int i = 0; i < SEG_LEN; i++) {
            int blk = s * SEG_LEN + i;
            if (blk < P1_BLOCKS) sum += cnt[blk * NBKT + t];
        }
    }
    segsum[s][t] = sum;
    __syncthreads();
    int tot = 0;
    if (s == 0) {
        int run = 0;
        for (int ss = 0; ss < NSEG; ss++) { int v = segsum[ss][t]; segsum[ss][t] = run; run += v; }
        tot = run;
        btot[t] = run;
    }
    __syncthreads();
    for (int off = 1; off < 256; off <<= 1) {
        int u = 0;
        if (s == 0 && t >= off) u = btot[t - off];
        __syncthreads();
        if (s == 0) btot[t] += u;
        __syncthreads();
    }
    if (s == 0) {
        int ex = btot[t] - tot;
        btot[t] = ex;
        if (t < NBKT) bbase[t] = ex;
    }
    __syncthreads();
    if (t < NBKT) {
        int run = btot[t] + segsum[s][t];
        for (int i = 0; i < SEG_LEN; i++) {
            int blk = s * SEG_LEN + i;
            if (blk < P1_BLOCKS) { int idx = blk * NBKT + t; int v = cnt[idx]; cnt[idx] = run; run += v; }
        }
    }
    if (threadIdx.x == 0) bbase[NBKT] = N_EDGES;
}

// ===== Pass 1: bin edges into bucket regions (LDS cursors only) =====
__global__ void bin_edges(const int* __restrict__ src, const int* __restrict__ dst,
                          const float* __restrict__ ew, const int* __restrict__ cnt,
                          int2* __restrict__ binned) {
    __shared__ int lcur[NBKT];
    int t = threadIdx.x;
    if (t < NBKT) lcur[t] = cnt[blockIdx.x * NBKT + t];
    __syncthreads();
    int e0 = blockIdx.x * P1_EDGES;
    for (int k = 0; k < P1_EDGES / 256; k++) {
        int e = e0 + k * 256 + t;
        if (e < N_EDGES) {
            int d = dst[e];
            int b = d >> BSHIFT;
            int pos = atomicAdd(&lcur[b], 1);
            binned[pos] = make_int2(src[e] | ((d & 255) << 16), __float_as_int(ew[e]));
        }
    }
}

// ===== Pass 2: sort each bucket by exact dst (LDS-staged), emit row_ptr + packed 4B edges =====
__global__ void sort_bucket(const int* __restrict__ bbase, const int2* __restrict__ binned,
                            unsigned* __restrict__ sorted, int* __restrict__ row_ptr) {
    __shared__ int2 buf[SORT_LDS_CAP];   // 40 KB
    __shared__ int nh[256];
    __shared__ int scn[256];
    __shared__ int lcur[256];
    int b = blockIdx.x;
    int t = threadIdx.x;
    int beg = bbase[b], end = bbase[b + 1];
    int n = end - beg;
    bool lds_path = (n <= SORT_LDS_CAP);
    nh[t] = 0;
    __syncthreads();
    if (lds_path) {
        for (int e = t; e < n; e += 256) {
            int2 v = binned[beg + e];
            buf[e] = v;
            atomicAdd(&nh[(v.x >> 16) & 255], 1);
        }
    } else {
        for (int e = beg + t; e < end; e += 256)
            atomicAdd(&nh[(binned[e].x >> 16) & 255], 1);
    }
    __syncthreads();
    int v = nh[t];
    scn[t] = v;
    __syncthreads();
    for (int off = 1; off < 256; off <<= 1) {
        int u = (t >= off) ? scn[t - off] : 0;
        __syncthreads();
        scn[t] += u;
        __syncthreads();
    }
    int ex = scn[t] - v;
    int node = (b << BSHIFT) + t;
    if (node < N_NODES) row_ptr[node] = beg + ex;
    __syncthreads();
    nh[t] = ex;
    lcur[t] = 0;
    __syncthreads();
    if (lds_path) {
        for (int e = t; e < n; e += 256) {
            int2 p = buf[e];
            int dlow = (p.x >> 16) & 255;
            int pos = beg + nh[dlow] + atomicAdd(&lcur[dlow], 1);
            unsigned hw = (unsigned)__half_as_ushort(__float2half(__int_as_float(p.y)));
            sorted[pos] = (unsigned)(p.x & 0xFFFF) | (hw << 16);
        }
    } else {
        for (int e = beg + t; e < end; e += 256) {
            int2 p = binned[e];
            int dlow = (p.x >> 16) & 255;
            int pos = beg + nh[dlow] + atomicAdd(&lcur[dlow], 1);
            unsigned hw = (unsigned)__half_as_ushort(__float2half(__int_as_float(p.y)));
            sorted[pos] = (unsigned)(p.x & 0xFFFF) | (hw << 16);
        }
    }
    if (b == 0 && t == 0) row_ptr[N_NODES] = N_EDGES;
}

__device__ __forceinline__ float edge_w(unsigned p) {
    return __half2float(__ushort_as_half((unsigned short)(p >> 16)));
}

// ====== Fused layer 1 -> t2 2-SLICED layout: t2s[slice][node][32] fp16 ======
#define L1_NPW 2
#define L1_NODES_PER_BLOCK (4 * 4 * L1_NPW)  // 32
__global__ void fused_l1(const int* __restrict__ row_ptr, const unsigned* __restrict__ sorted,
                         const float* __restrict__ x, const float* __restrict__ W1,
                         const float* __restrict__ b1, const float* __restrict__ W2,
                         __half* __restrict__ t2s) {
    __shared__ float w2s[128 * 64];
    __shared__ float hls[4][4][128];
    for (int k = threadIdx.x; k < 128 * 64; k += 256) w2s[k] = W2[k];
    int wave = threadIdx.x >> 6;
    int lane = threadIdx.x & 63;
    float w1a = W1[lane],      w1b = W1[128 + lane];
    float w1c = W1[64 + lane], w1d = W1[192 + lane];
    float b1lo = b1[lane], b1hi = b1[64 + lane];
    __syncthreads();

    int sub = lane >> 4;
    int sl  = lane & 15;
    // sliced store offset for this lane's feature (feat = lane): slice = lane>>5
    long soff = (long)(lane >> 5) * (N_NODES * 32) + (lane & 31);

    for (int it = 0; it < L1_NPW; it++) {
        int base = blockIdx.x * L1_NODES_PER_BLOCK + wave * (4 * L1_NPW) + it * 4;
        int gnode = base + sub;
        float a0 = 0.f, a1 = 0.f;
        if (gnode < N_NODES) {
            int beg = row_ptr[gnode], end = row_ptr[gnode + 1];
            for (int e = beg + sl; e < end; e += 16) {
                unsigned p = sorted[e];
                float w = edge_w(p);
                float2 xv = ((const float2*)x)[p & 0xFFFF];
                a0 = fmaf(w, xv.x, a0);
                a1 = fmaf(w, xv.y, a1);
            }
        }
#pragma unroll
        for (int off = 1; off < 16; off <<= 1) {
            a0 += __shfl_xor(a0, off);
            a1 += __shfl_xor(a1, off);
        }
#pragma unroll
        for (int n = 0; n < 4; n++) {
            float an0 = __shfl(a0, 16 * n);
            float an1 = __shfl(a1, 16 * n);
            float hlo = fmaxf(fmaf(an0, w1a, fmaf(an1, w1b, b1lo)), 0.f);
            float hhi = fmaxf(fmaf(an0, w1c, fmaf(an1, w1d, b1hi)), 0.f);
            hls[wave][n][lane] = hlo;
            hls[wave][n][64 + lane] = hhi;
        }
        float acc0 = 0.f, acc1 = 0.f, acc2 = 0.f, acc3 = 0.f;
#pragma unroll 4
        for (int k4 = 0; k4 < 32; k4++) {
            float w0 = w2s[(4 * k4 + 0) * 64 + lane];
            float w1 = w2s[(4 * k4 + 1) * 64 + lane];
            float w2 = w2s[(4 * k4 + 2) * 64 + lane];
            float w3 = w2s[(4 * k4 + 3) * 64 + lane];
            float4 h0 = *(const float4*)&hls[wave][0][4 * k4];
            float4 h1 = *(const float4*)&hls[wave][1][4 * k4];
            float4 h2 = *(const float4*)&hls[wave][2][4 * k4];
            float4 h3 = *(const float4*)&hls[wave][3][4 * k4];
            acc0 = fmaf(h0.x, w0, fmaf(h0.y, w1, fmaf(h0.z, w2, fmaf(h0.w, w3, acc0))));
            acc1 = fmaf(h1.x, w0, fmaf(h1.y, w1, fmaf(h1.z, w2, fmaf(h1.w, w3, acc1))));
            acc2 = fmaf(h2.x, w0, fmaf(h2.y, w1, fmaf(h2.z, w2, fmaf(h2.w, w3, acc2))));
            acc3 = fmaf(h3.x, w0, fmaf(h3.y, w1, fmaf(h3.z, w2, fmaf(h3.w, w3, acc3))));
        }
        if (base + 0 < N_NODES) t2s[soff + (long)(base + 0) * 32] = __float2half(acc0);
        if (base + 1 < N_NODES) t2s[soff + (long)(base + 1) * 32] = __float2half(acc1);
        if (base + 2 < N_NODES) t2s[soff + (long)(base + 2) * 32] = __float2half(acc2);
        if (base + 3 < N_NODES) t2s[soff + (long)(base + 3) * 32] = __float2half(acc3);
    }
}

// ====== Layer 2 gather, 2-sliced: slice = blockIdx&1 -> even/odd XCDs each own 3.2MB slice ======
// Wave = 2 nodes x 32 feature-lanes; per edge one contiguous 64B row chunk (1 cache line).
// relu(acc+b2_slice)·W3_slice reduced over 32 lanes, atomicAdd into t3[node].
__global__ void gather2_half(const int* __restrict__ row_ptr, const unsigned* __restrict__ sorted,
                             const __half* __restrict__ t2s, const float* __restrict__ b2,
                             const float* __restrict__ W3, float* __restrict__ t3) {
    int slice = blockIdx.x & 1;
    int chunk = blockIdx.x >> 1;
    int wave = threadIdx.x >> 6;
    int lane = threadIdx.x & 63;
    int half = lane >> 5;        // node within wave
    int fl   = lane & 31;        // feature within slice
    int node = chunk * 8 + wave * 2 + half;
    if (node >= N_NODES) return;
    const __half* sb = t2s + (long)slice * (N_NODES * 32);
    int beg = row_ptr[node], end = row_ptr[node + 1];
    float accA = 0.f, accB = 0.f;
    int e = beg;
    for (; e + 1 < end; e += 2) {
        unsigned p0 = sorted[e];
        unsigned p1 = sorted[e + 1];
        float v0 = __half2float(sb[(p0 & 0xFFFF) * 32 + fl]);
        float v1 = __half2float(sb[(p1 & 0xFFFF) * 32 + fl]);
        accA = fmaf(edge_w(p0), v0, accA);
        accB = fmaf(edge_w(p1), v1, accB);
    }
    if (e < end) {
        unsigned p = sorted[e];
        accA = fmaf(edge_w(p), __half2float(sb[(p & 0xFFFF) * 32 + fl]), accA);
    }
    float h = fmaxf(accA + accB + b2[slice * 32 + fl], 0.f) * W3[slice * 32 + fl];
#pragma unroll
    for (int off = 1; off < 32; off <<= 1) h += __shfl_xor(h, off);  // stays within 32-lane group
    if (fl == 0) atomicAdd(&t3[node], h);
}

// ====== Layer 3: gather scalar t3 ======
__global__ void gather3(const int* __restrict__ row_ptr, const unsigned* __restrict__ sorted,
                        const float* __restrict__ t3, const float* __restrict__ b3,
                        float* __restrict__ out) {
    int i = blockIdx.x * blockDim.x + threadIdx.x;
    if (i >= N_NODES) return;
    int beg = row_ptr[i], end = row_ptr[i + 1];
    float acc = 0.f;
    for (int e = beg; e < end; e++) {
        unsigned p = sorted[e];
        acc = fmaf(edge_w(p), t3[p & 0xFFFF], acc);
    }
    out[i] = acc + b3[0];
}

extern "C" void kernel_launch(void* const* d_in, const int* in_sizes, int n_in,
                              void* d_out, int out_size, void* d_ws, size_t ws_size,
                              hipStream_t stream) {
    const float* x  = (const float*)d_in[0];
    const int*   ei = (const int*)d_in[1];     // [2, E]
    const float* ew = (const float*)d_in[2];
    const float* W1 = (const float*)d_in[3];
    const float* b1 = (const float*)d_in[4];
    const float* W2 = (const float*)d_in[5];
    const float* b2 = (const float*)d_in[6];
    const float* W3 = (const float*)d_in[7];
    const float* b3 = (const float*)d_in[8];
    float* out = (float*)d_out;

    const int* src = ei;
    const int* dst = ei + N_EDGES;

    // workspace layout
    char* p = (char*)d_ws;
    int*  cnt     = (int*)p;            p += P1_BLOCKS * NBKT * sizeof(int);
    int*  bbase   = (int*)p;            p += (NBKT + 1) * sizeof(int);
    int*  row_ptr = (int*)p;            p += (N_NODES + 1) * sizeof(int);
    p = (char*)(((uintptr_t)p + 15) & ~(uintptr_t)15);
    int2* binned      = (int2*)p;       p += N_EDGES * sizeof(int2);            // 6.4 MB
    unsigned* sorted  = (unsigned*)p;   p += N_EDGES * sizeof(unsigned);        // 3.2 MB
    __half* t2s   = (__half*)p;         p += 2L * N_NODES * 32 * sizeof(__half);// 6.4 MB
    float* t3     = (float*)p;          p += N_NODES * sizeof(float);

    // CSR build: count matrix -> cursor scan -> bin -> per-bucket sort
    count_kernel<<<P1_BLOCKS, 256, 0, stream>>>(dst, cnt);
    scan_matrix<<<1, 1024, 0, stream>>>(cnt, bbase);
    bin_edges<<<P1_BLOCKS, 256, 0, stream>>>(src, dst, ew, cnt, binned);
    sort_bucket<<<NBKT, 256, 0, stream>>>(bbase, binned, sorted, row_ptr);

    // Layer 1 (fused gather + dense 2->128 + relu + dense 128->64, 2-sliced fp16 out)
    fused_l1<<<(N_NODES + L1_NODES_PER_BLOCK - 1) / L1_NODES_PER_BLOCK, 256, 0, stream>>>(
        row_ptr, sorted, x, W1, b1, W2, t2s);

    // Layer 2 gather + fused layer-3 projection (2-sliced, L2-resident per XCD parity)
    hipMemsetAsync(t3, 0, N_NODES * sizeof(float), stream);
    gather2_half<<<((N_NODES + 7) / 8) * 2, 256, 0, stream>>>(row_ptr, sorted, t2s, b2, W3, t3);

    // Layer 3
    gather3<<<(N_NODES + 255) / 256, 256, 0, stream>>>(row_ptr, sorted, t3, b3, out);
}

// Round 9
// 179.352 us; speedup vs baseline: 1.1182x; 1.1182x over previous
//
#include <hip/hip_runtime.h>
#include <hip/hip_fp16.h>

#define N_NODES 50000
#define N_EDGES 800000
#define BSHIFT 8
#define NBKT ((N_NODES + 255) >> BSHIFT)                 // 196 buckets of 256 nodes
#define P1_EDGES 4096
#define P1_BLOCKS ((N_EDGES + P1_EDGES - 1) / P1_EDGES)  // 196
#define NSEG 4
#define SEG_LEN ((P1_BLOCKS + NSEG - 1) / NSEG)          // 49
#define SORT_LDS_CAP 5000                                 // 40 KB; bucket mean 4082

// ===== Pass 0: per-block bucket counts -> cnt[blk][bucket] =====
__global__ void count_kernel(const int* __restrict__ dst, int* __restrict__ cnt) {
    __shared__ int h[NBKT];
    int t = threadIdx.x;
    if (t < NBKT) h[t] = 0;
    __syncthreads();
    int e0 = blockIdx.x * P1_EDGES;
    for (int k = 0; k < P1_EDGES / 256; k++) {
        int e = e0 + k * 256 + t;
        if (e < N_EDGES) atomicAdd(&h[dst[e] >> BSHIFT], 1);
    }
    __syncthreads();
    if (t < NBKT) cnt[blockIdx.x * NBKT + t] = h[t];
}

// ===== Pass 0.5: cnt -> exact per-(block,bucket) cursors; bucket bases. 4-way segmented. =====
__global__ void scan_matrix(int* __restrict__ cnt, int* __restrict__ bbase) {
    __shared__ int segsum[NSEG][256];
    __shared__ int btot[256];
    int t = threadIdx.x & 255;   // bucket
    int s = threadIdx.x >> 8;    // segment
    int sum = 0;
    if (t < NBKT) {
        for (int i = 0; i < SEG_LEN; i++) {
            int blk = s * SEG_LEN + i;
            if (blk < P1_BLOCKS) sum += cnt[blk * NBKT + t];
        }
    }
    segsum[s][t] = sum;
    __syncthreads();
    int tot = 0;
    if (s == 0) {
        int run = 0;
        for (int ss = 0; ss < NSEG; ss++) { int v = segsum[ss][t]; segsum[ss][t] = run; run += v; }
        tot = run;
        btot[t] = run;
    }
    __syncthreads();
    for (int off = 1; off < 256; off <<= 1) {
        int u = 0;
        if (s == 0 && t >= off) u = btot[t - off];
        __syncthreads();
        if (s == 0) btot[t] += u;
        __syncthreads();
    }
    if (s == 0) {
        int ex = btot[t] - tot;
        btot[t] = ex;
        if (t < NBKT) bbase[t] = ex;
    }
    __syncthreads();
    if (t < NBKT) {
        int run = btot[t] + segsum[s][t];
        for (int i = 0; i < SEG_LEN; i++) {
            int blk = s * SEG_LEN + i;
            if (blk < P1_BLOCKS) { int idx = blk * NBKT + t; int v = cnt[idx]; cnt[idx] = run; run += v; }
        }
    }
    if (threadIdx.x == 0) bbase[NBKT] = N_EDGES;
}

// ===== Pass 1: bin edges into bucket regions (LDS cursors only) =====
__global__ void bin_edges(const int* __restrict__ src, const int* __restrict__ dst,
                          const float* __restrict__ ew, const int* __restrict__ cnt,
                          int2* __restrict__ binned) {
    __shared__ int lcur[NBKT];
    int t = threadIdx.x;
    if (t < NBKT) lcur[t] = cnt[blockIdx.x * NBKT + t];
    __syncthreads();
    int e0 = blockIdx.x * P1_EDGES;
    for (int k = 0; k < P1_EDGES / 256; k++) {
        int e = e0 + k * 256 + t;
        if (e < N_EDGES) {
            int d = dst[e];
            int b = d >> BSHIFT;
            int pos = atomicAdd(&lcur[b], 1);
            binned[pos] = make_int2(src[e] | ((d & 255) << 16), __float_as_int(ew[e]));
        }
    }
}

// ===== Pass 2: sort each bucket by exact dst (LDS-staged), emit row_ptr + packed 4B edges =====
__global__ void sort_bucket(const int* __restrict__ bbase, const int2* __restrict__ binned,
                            unsigned* __restrict__ sorted, int* __restrict__ row_ptr) {
    __shared__ int2 buf[SORT_LDS_CAP];   // 40 KB
    __shared__ int nh[256];
    __shared__ int scn[256];
    __shared__ int lcur[256];
    int b = blockIdx.x;
    int t = threadIdx.x;
    int beg = bbase[b], end = bbase[b + 1];
    int n = end - beg;
    bool lds_path = (n <= SORT_LDS_CAP);
    nh[t] = 0;
    __syncthreads();
    if (lds_path) {
        for (int e = t; e < n; e += 256) {
            int2 v = binned[beg + e];
            buf[e] = v;
            atomicAdd(&nh[(v.x >> 16) & 255], 1);
        }
    } else {
        for (int e = beg + t; e < end; e += 256)
            atomicAdd(&nh[(binned[e].x >> 16) & 255], 1);
    }
    __syncthreads();
    int v = nh[t];
    scn[t] = v;
    __syncthreads();
    for (int off = 1; off < 256; off <<= 1) {
        int u = (t >= off) ? scn[t - off] : 0;
        __syncthreads();
        scn[t] += u;
        __syncthreads();
    }
    int ex = scn[t] - v;
    int node = (b << BSHIFT) + t;
    if (node < N_NODES) row_ptr[node] = beg + ex;
    __syncthreads();
    nh[t] = ex;
    lcur[t] = 0;
    __syncthreads();
    if (lds_path) {
        for (int e = t; e < n; e += 256) {
            int2 p = buf[e];
            int dlow = (p.x >> 16) & 255;
            int pos = beg + nh[dlow] + atomicAdd(&lcur[dlow], 1);
            unsigned hw = (unsigned)__half_as_ushort(__float2half(__int_as_float(p.y)));
            sorted[pos] = (unsigned)(p.x & 0xFFFF) | (hw << 16);
        }
    } else {
        for (int e = beg + t; e < end; e += 256) {
            int2 p = binned[e];
            int dlow = (p.x >> 16) & 255;
            int pos = beg + nh[dlow] + atomicAdd(&lcur[dlow], 1);
            unsigned hw = (unsigned)__half_as_ushort(__float2half(__int_as_float(p.y)));
            sorted[pos] = (unsigned)(p.x & 0xFFFF) | (hw << 16);
        }
    }
    if (b == 0 && t == 0) row_ptr[N_NODES] = N_EDGES;
}

__device__ __forceinline__ float edge_w(unsigned p) {
    return __half2float(__ushort_as_half((unsigned short)(p >> 16)));
}

// ====== Fused layer 1: gather x -> h1 = relu(.@W1+b1) -> t2 = h1 @ W2 (fp16 plain [node][64]) ======
#define L1_NPW 2
#define L1_NODES_PER_BLOCK (4 * 4 * L1_NPW)  // 32
__global__ void fused_l1(const int* __restrict__ row_ptr, const unsigned* __restrict__ sorted,
                         const float* __restrict__ x, const float* __restrict__ W1,
                         const float* __restrict__ b1, const float* __restrict__ W2,
                         __half* __restrict__ t2) {
    __shared__ float w2s[128 * 64];
    __shared__ float hls[4][4][128];
    for (int k = threadIdx.x; k < 128 * 64; k += 256) w2s[k] = W2[k];
    int wave = threadIdx.x >> 6;
    int lane = threadIdx.x & 63;
    float w1a = W1[lane],      w1b = W1[128 + lane];
    float w1c = W1[64 + lane], w1d = W1[192 + lane];
    float b1lo = b1[lane], b1hi = b1[64 + lane];
    __syncthreads();

    int sub = lane >> 4;
    int sl  = lane & 15;

    for (int it = 0; it < L1_NPW; it++) {
        int base = blockIdx.x * L1_NODES_PER_BLOCK + wave * (4 * L1_NPW) + it * 4;
        int gnode = base + sub;
        float a0 = 0.f, a1 = 0.f;
        if (gnode < N_NODES) {
            int beg = row_ptr[gnode], end = row_ptr[gnode + 1];
            for (int e = beg + sl; e < end; e += 16) {
                unsigned p = sorted[e];
                float w = edge_w(p);
                float2 xv = ((const float2*)x)[p & 0xFFFF];
                a0 = fmaf(w, xv.x, a0);
                a1 = fmaf(w, xv.y, a1);
            }
        }
#pragma unroll
        for (int off = 1; off < 16; off <<= 1) {
            a0 += __shfl_xor(a0, off);
            a1 += __shfl_xor(a1, off);
        }
#pragma unroll
        for (int n = 0; n < 4; n++) {
            float an0 = __shfl(a0, 16 * n);
            float an1 = __shfl(a1, 16 * n);
            float hlo = fmaxf(fmaf(an0, w1a, fmaf(an1, w1b, b1lo)), 0.f);
            float hhi = fmaxf(fmaf(an0, w1c, fmaf(an1, w1d, b1hi)), 0.f);
            hls[wave][n][lane] = hlo;
            hls[wave][n][64 + lane] = hhi;
        }
        float acc0 = 0.f, acc1 = 0.f, acc2 = 0.f, acc3 = 0.f;
#pragma unroll 4
        for (int k4 = 0; k4 < 32; k4++) {
            float w0 = w2s[(4 * k4 + 0) * 64 + lane];
            float w1 = w2s[(4 * k4 + 1) * 64 + lane];
            float w2 = w2s[(4 * k4 + 2) * 64 + lane];
            float w3 = w2s[(4 * k4 + 3) * 64 + lane];
            float4 h0 = *(const float4*)&hls[wave][0][4 * k4];
            float4 h1 = *(const float4*)&hls[wave][1][4 * k4];
            float4 h2 = *(const float4*)&hls[wave][2][4 * k4];
            float4 h3 = *(const float4*)&hls[wave][3][4 * k4];
            acc0 = fmaf(h0.x, w0, fmaf(h0.y, w1, fmaf(h0.z, w2, fmaf(h0.w, w3, acc0))));
            acc1 = fmaf(h1.x, w0, fmaf(h1.y, w1, fmaf(h1.z, w2, fmaf(h1.w, w3, acc1))));
            acc2 = fmaf(h2.x, w0, fmaf(h2.y, w1, fmaf(h2.z, w2, fmaf(h2.w, w3, acc2))));
            acc3 = fmaf(h3.x, w0, fmaf(h3.y, w1, fmaf(h3.z, w2, fmaf(h3.w, w3, acc3))));
        }
        if (base + 0 < N_NODES) t2[(base + 0) * 64 + lane] = __float2half(acc0);
        if (base + 1 < N_NODES) t2[(base + 1) * 64 + lane] = __float2half(acc1);
        if (base + 2 < N_NODES) t2[(base + 2) * 64 + lane] = __float2half(acc2);
        if (base + 3 < N_NODES) t2[(base + 3) * 64 + lane] = __float2half(acc3);
    }
}

// ====== Layer 2 gather v3: wave per node, 4 edges per load instruction ======
// lane = eg(2b) * 16 + fli(4b): edge-group eg handles edges beg+eg+4k; lane loads
// uint2 = 4 fp16 feats at [fli*4 .. fli*4+4). One wave instr = 512 B = 4 edges.
// Reduce over eg (shfl 16,32), fuse relu+b2+W3 (4 feats/lane), reduce over fli.
__global__ void gather2_dot3(const int* __restrict__ row_ptr, const unsigned* __restrict__ sorted,
                             const __half* __restrict__ t2, const float* __restrict__ b2,
                             const float* __restrict__ W3, float* __restrict__ t3) {
    int gtid = blockIdx.x * blockDim.x + threadIdx.x;
    int node = gtid >> 6;
    int lane = threadIdx.x & 63;
    if (node >= N_NODES) return;
    int eg  = lane >> 4;
    int fli = lane & 15;
    int beg = row_ptr[node], end = row_ptr[node + 1];
    float a0 = 0.f, a1 = 0.f, a2 = 0.f, a3 = 0.f;
    int e = beg + eg;
    for (; e + 4 < end; e += 8) {
        unsigned p0 = sorted[e];
        unsigned p1 = sorted[e + 4];
        uint2 q0 = *(const uint2*)(t2 + (p0 & 0xFFFF) * 64 + fli * 4);
        uint2 q1 = *(const uint2*)(t2 + (p1 & 0xFFFF) * 64 + fli * 4);
        float w0 = edge_w(p0), w1 = edge_w(p1);
        float2 f00 = __half22float2(*(const __half2*)&q0.x);
        float2 f01 = __half22float2(*(const __half2*)&q0.y);
        float2 f10 = __half22float2(*(const __half2*)&q1.x);
        float2 f11 = __half22float2(*(const __half2*)&q1.y);
        a0 = fmaf(w0, f00.x, a0); a1 = fmaf(w0, f00.y, a1);
        a2 = fmaf(w0, f01.x, a2); a3 = fmaf(w0, f01.y, a3);
        a0 = fmaf(w1, f10.x, a0); a1 = fmaf(w1, f10.y, a1);
        a2 = fmaf(w1, f11.x, a2); a3 = fmaf(w1, f11.y, a3);
    }
    if (e < end) {
        unsigned p = sorted[e];
        uint2 q = *(const uint2*)(t2 + (p & 0xFFFF) * 64 + fli * 4);
        float w = edge_w(p);
        float2 f0 = __half22float2(*(const __half2*)&q.x);
        float2 f1 = __half22float2(*(const __half2*)&q.y);
        a0 = fmaf(w, f0.x, a0); a1 = fmaf(w, f0.y, a1);
        a2 = fmaf(w, f1.x, a2); a3 = fmaf(w, f1.y, a3);
    }
    // reduce across the 4 edge groups
#pragma unroll
    for (int off = 16; off < 64; off <<= 1) {
        a0 += __shfl_xor(a0, off); a1 += __shfl_xor(a1, off);
        a2 += __shfl_xor(a2, off); a3 += __shfl_xor(a3, off);
    }
    float4 bb = *(const float4*)(b2 + fli * 4);
    float4 ww = *(const float4*)(W3 + fli * 4);
    float h = fmaxf(a0 + bb.x, 0.f) * ww.x + fmaxf(a1 + bb.y, 0.f) * ww.y +
              fmaxf(a2 + bb.z, 0.f) * ww.z + fmaxf(a3 + bb.w, 0.f) * ww.w;
#pragma unroll
    for (int off = 1; off < 16; off <<= 1) h += __shfl_xor(h, off);
    if (lane == 0) t3[node] = h;
}

// ====== Layer 3: gather scalar t3 ======
__global__ void gather3(const int* __restrict__ row_ptr, const unsigned* __restrict__ sorted,
                        const float* __restrict__ t3, const float* __restrict__ b3,
                        float* __restrict__ out) {
    int i = blockIdx.x * blockDim.x + threadIdx.x;
    if (i >= N_NODES) return;
    int beg = row_ptr[i], end = row_ptr[i + 1];
    float acc = 0.f;
    for (int e = beg; e < end; e++) {
        unsigned p = sorted[e];
        acc = fmaf(edge_w(p), t3[p & 0xFFFF], acc);
    }
    out[i] = acc + b3[0];
}

extern "C" void kernel_launch(void* const* d_in, const int* in_sizes, int n_in,
                              void* d_out, int out_size, void* d_ws, size_t ws_size,
                              hipStream_t stream) {
    const float* x  = (const float*)d_in[0];
    const int*   ei = (const int*)d_in[1];     // [2, E]
    const float* ew = (const float*)d_in[2];
    const float* W1 = (const float*)d_in[3];
    const float* b1 = (const float*)d_in[4];
    const float* W2 = (const float*)d_in[5];
    const float* b2 = (const float*)d_in[6];
    const float* W3 = (const float*)d_in[7];
    const float* b3 = (const float*)d_in[8];
    float* out = (float*)d_out;

    const int* src = ei;
    const int* dst = ei + N_EDGES;

    // workspace layout
    char* p = (char*)d_ws;
    int*  cnt     = (int*)p;            p += P1_BLOCKS * NBKT * sizeof(int);
    int*  bbase   = (int*)p;            p += (NBKT + 1) * sizeof(int);
    int*  row_ptr = (int*)p;            p += (N_NODES + 1) * sizeof(int);
    p = (char*)(((uintptr_t)p + 15) & ~(uintptr_t)15);
    int2* binned      = (int2*)p;       p += N_EDGES * sizeof(int2);          // 6.4 MB
    unsigned* sorted  = (unsigned*)p;   p += N_EDGES * sizeof(unsigned);      // 3.2 MB
    __half* t2    = (__half*)p;         p += 64L * N_NODES * sizeof(__half);  // 6.4 MB
    float* t3     = (float*)p;          p += N_NODES * sizeof(float);

    // CSR build: count matrix -> cursor scan -> bin -> per-bucket sort
    count_kernel<<<P1_BLOCKS, 256, 0, stream>>>(dst, cnt);
    scan_matrix<<<1, 1024, 0, stream>>>(cnt, bbase);
    bin_edges<<<P1_BLOCKS, 256, 0, stream>>>(src, dst, ew, cnt, binned);
    sort_bucket<<<NBKT, 256, 0, stream>>>(bbase, binned, sorted, row_ptr);

    // Layer 1 (fused gather + dense 2->128 + relu + dense 128->64, fp16 out)
    fused_l1<<<(N_NODES + L1_NODES_PER_BLOCK - 1) / L1_NODES_PER_BLOCK, 256, 0, stream>>>(
        row_ptr, sorted, x, W1, b1, W2, t2);

    // Layer 2 gather + fused layer-3 projection
    gather2_dot3<<<(N_NODES * 64 + 255) / 256, 256, 0, stream>>>(row_ptr, sorted, t2, b2, W3, t3);

    // Layer 3
    gather3<<<(N_NODES + 255) / 256, 256, 0, stream>>>(row_ptr, sorted, t3, b3, out);
}

// Round 10
// 171.329 us; speedup vs baseline: 1.1706x; 1.0468x over previous
//
#include <hip/hip_runtime.h>
#include <hip/hip_fp16.h>

#define N_NODES 50000
#define N_EDGES 800000
#define BSHIFT 8
#define NBKT ((N_NODES + 255) >> BSHIFT)                 // 196 buckets of 256 nodes
#define CAP 8192                                          // fixed bucket capacity (mean 4082, sigma 64)
#define P1_EDGES 4096
#define P1_BLOCKS ((N_EDGES + P1_EDGES - 1) / P1_EDGES)  // 196
#define SORT_LDS_CAP 5000                                 // 40 KB LDS staging

// ===== Pass 1: bin edges into fixed-capacity bucket regions =====
// Per-block LDS count -> one global atomicAdd reservation per (block,bucket) -> LDS-cursor write.
// binned payload: {src | (dst&255)<<16, bits(w)}
__global__ void bin_edges(const int* __restrict__ src, const int* __restrict__ dst,
                          const float* __restrict__ ew, int* __restrict__ bcur,
                          int2* __restrict__ binned) {
    __shared__ int cnt[NBKT];
    __shared__ int cbase[NBKT];
    int t = threadIdx.x;
    if (t < NBKT) cnt[t] = 0;
    __syncthreads();
    int e0 = blockIdx.x * P1_EDGES;
    for (int k = 0; k < P1_EDGES / 256; k++) {
        int e = e0 + k * 256 + t;
        if (e < N_EDGES) atomicAdd(&cnt[dst[e] >> BSHIFT], 1);
    }
    __syncthreads();
    if (t < NBKT) {
        int v = cnt[t];
        int base = v ? atomicAdd(&bcur[t], v) : 0;
        cbase[t] = t * CAP + base;
        cnt[t] = 0;                   // reuse as local cursor
    }
    __syncthreads();
    for (int k = 0; k < P1_EDGES / 256; k++) {
        int e = e0 + k * 256 + t;
        if (e < N_EDGES) {
            int d = dst[e];
            int b = d >> BSHIFT;
            int pos = cbase[b] + atomicAdd(&cnt[b], 1);
            binned[pos] = make_int2(src[e] | ((d & 255) << 16), __float_as_int(ew[e]));
        }
    }
}

// ===== Pass 2: sort each bucket by exact dst (LDS-staged), emit rowspan + packed 4B edges =====
// packed edge: src(16) | fp16 weight(16).  rowspan[node] = {beg, end} into `sorted`.
__global__ void sort_bucket(const int* __restrict__ bcur, const int2* __restrict__ binned,
                            unsigned* __restrict__ sorted, int2* __restrict__ rowspan) {
    __shared__ int2 buf[SORT_LDS_CAP];   // 40 KB
    __shared__ int nh[256];
    __shared__ int scn[256];
    __shared__ int lcur[256];
    int b = blockIdx.x;
    int t = threadIdx.x;
    int base = b * CAP;
    int n = bcur[b];
    if (n > CAP) n = CAP;                // unreachable with 60-sigma headroom; safety only
    bool lds_path = (n <= SORT_LDS_CAP);
    nh[t] = 0;
    __syncthreads();
    if (lds_path) {
        for (int e = t; e < n; e += 256) {
            int2 v = binned[base + e];
            buf[e] = v;
            atomicAdd(&nh[(v.x >> 16) & 255], 1);
        }
    } else {
        for (int e = t; e < n; e += 256)
            atomicAdd(&nh[(binned[base + e].x >> 16) & 255], 1);
    }
    __syncthreads();
    int v = nh[t];
    scn[t] = v;
    __syncthreads();
    for (int off = 1; off < 256; off <<= 1) {
        int u = (t >= off) ? scn[t - off] : 0;
        __syncthreads();
        scn[t] += u;
        __syncthreads();
    }
    int ex = scn[t] - v;
    int node = (b << BSHIFT) + t;
    if (node < N_NODES) rowspan[node] = make_int2(base + ex, base + ex + v);
    __syncthreads();
    nh[t] = ex;
    lcur[t] = 0;
    __syncthreads();
    if (lds_path) {
        for (int e = t; e < n; e += 256) {
            int2 p = buf[e];
            int dlow = (p.x >> 16) & 255;
            int pos = base + nh[dlow] + atomicAdd(&lcur[dlow], 1);
            unsigned hw = (unsigned)__half_as_ushort(__float2half(__int_as_float(p.y)));
            sorted[pos] = (unsigned)(p.x & 0xFFFF) | (hw << 16);
        }
    } else {
        for (int e = t; e < n; e += 256) {
            int2 p = binned[base + e];
            int dlow = (p.x >> 16) & 255;
            int pos = base + nh[dlow] + atomicAdd(&lcur[dlow], 1);
            unsigned hw = (unsigned)__half_as_ushort(__float2half(__int_as_float(p.y)));
            sorted[pos] = (unsigned)(p.x & 0xFFFF) | (hw << 16);
        }
    }
}

__device__ __forceinline__ float edge_w(unsigned p) {
    return __half2float(__ushort_as_half((unsigned short)(p >> 16)));
}

// ====== Fused layer 1: gather x -> h1 = relu(.@W1+b1) -> t2 = h1 @ W2 (fp16 [node][64]) ======
#define L1_NPW 2
#define L1_NODES_PER_BLOCK (4 * 4 * L1_NPW)  // 32
__global__ void fused_l1(const int2* __restrict__ rowspan, const unsigned* __restrict__ sorted,
                         const float* __restrict__ x, const float* __restrict__ W1,
                         const float* __restrict__ b1, const float* __restrict__ W2,
                         __half* __restrict__ t2) {
    __shared__ float w2s[128 * 64];
    __shared__ float hls[4][4][128];
    for (int k = threadIdx.x; k < 128 * 64; k += 256) w2s[k] = W2[k];
    int wave = threadIdx.x >> 6;
    int lane = threadIdx.x & 63;
    float w1a = W1[lane],      w1b = W1[128 + lane];
    float w1c = W1[64 + lane], w1d = W1[192 + lane];
    float b1lo = b1[lane], b1hi = b1[64 + lane];
    __syncthreads();

    int sub = lane >> 4;
    int sl  = lane & 15;

    for (int it = 0; it < L1_NPW; it++) {
        int base = blockIdx.x * L1_NODES_PER_BLOCK + wave * (4 * L1_NPW) + it * 4;
        int gnode = base + sub;
        float a0 = 0.f, a1 = 0.f;
        if (gnode < N_NODES) {
            int2 sp = rowspan[gnode];
            for (int e = sp.x + sl; e < sp.y; e += 16) {
                unsigned p = sorted[e];
                float w = edge_w(p);
                float2 xv = ((const float2*)x)[p & 0xFFFF];
                a0 = fmaf(w, xv.x, a0);
                a1 = fmaf(w, xv.y, a1);
            }
        }
#pragma unroll
        for (int off = 1; off < 16; off <<= 1) {
            a0 += __shfl_xor(a0, off);
            a1 += __shfl_xor(a1, off);
        }
#pragma unroll
        for (int n = 0; n < 4; n++) {
            float an0 = __shfl(a0, 16 * n);
            float an1 = __shfl(a1, 16 * n);
            float hlo = fmaxf(fmaf(an0, w1a, fmaf(an1, w1b, b1lo)), 0.f);
            float hhi = fmaxf(fmaf(an0, w1c, fmaf(an1, w1d, b1hi)), 0.f);
            hls[wave][n][lane] = hlo;
            hls[wave][n][64 + lane] = hhi;
        }
        float acc0 = 0.f, acc1 = 0.f, acc2 = 0.f, acc3 = 0.f;
#pragma unroll 4
        for (int k4 = 0; k4 < 32; k4++) {
            float w0 = w2s[(4 * k4 + 0) * 64 + lane];
            float w1 = w2s[(4 * k4 + 1) * 64 + lane];
            float w2 = w2s[(4 * k4 + 2) * 64 + lane];
            float w3 = w2s[(4 * k4 + 3) * 64 + lane];
            float4 h0 = *(const float4*)&hls[wave][0][4 * k4];
            float4 h1 = *(const float4*)&hls[wave][1][4 * k4];
            float4 h2 = *(const float4*)&hls[wave][2][4 * k4];
            float4 h3 = *(const float4*)&hls[wave][3][4 * k4];
            acc0 = fmaf(h0.x, w0, fmaf(h0.y, w1, fmaf(h0.z, w2, fmaf(h0.w, w3, acc0))));
            acc1 = fmaf(h1.x, w0, fmaf(h1.y, w1, fmaf(h1.z, w2, fmaf(h1.w, w3, acc1))));
            acc2 = fmaf(h2.x, w0, fmaf(h2.y, w1, fmaf(h2.z, w2, fmaf(h2.w, w3, acc2))));
            acc3 = fmaf(h3.x, w0, fmaf(h3.y, w1, fmaf(h3.z, w2, fmaf(h3.w, w3, acc3))));
        }
        if (base + 0 < N_NODES) t2[(base + 0) * 64 + lane] = __float2half(acc0);
        if (base + 1 < N_NODES) t2[(base + 1) * 64 + lane] = __float2half(acc1);
        if (base + 2 < N_NODES) t2[(base + 2) * 64 + lane] = __float2half(acc2);
        if (base + 3 < N_NODES) t2[(base + 3) * 64 + lane] = __float2half(acc3);
    }
}

// ====== Layer 2 gather v4: wave per node, 8 edges per load instruction ======
// lane = eg(3b)*8 + fli(3b): 8 fli lanes x uint4 = full 128B row per edge; 8 edge groups.
// Reduce over eg (shfl 8,16,32), fuse relu+b2+W3 (8 feats/lane), reduce over fli (1,2,4).
__global__ void gather2_dot3(const int2* __restrict__ rowspan, const unsigned* __restrict__ sorted,
                             const __half* __restrict__ t2, const float* __restrict__ b2,
                             const float* __restrict__ W3, float* __restrict__ t3) {
    int gtid = blockIdx.x * blockDim.x + threadIdx.x;
    int node = gtid >> 6;
    int lane = threadIdx.x & 63;
    if (node >= N_NODES) return;
    int eg  = lane >> 3;
    int fli = lane & 7;
    int2 sp = rowspan[node];
    float a0 = 0.f, a1 = 0.f, a2 = 0.f, a3 = 0.f, a4 = 0.f, a5 = 0.f, a6 = 0.f, a7 = 0.f;
    int e = sp.x + eg;
    for (; e + 8 < sp.y; e += 16) {
        unsigned p0 = sorted[e];
        unsigned p1 = sorted[e + 8];
        uint4 q0 = *(const uint4*)(t2 + (p0 & 0xFFFF) * 64 + fli * 8);
        uint4 q1 = *(const uint4*)(t2 + (p1 & 0xFFFF) * 64 + fli * 8);
        float w0 = edge_w(p0), w1 = edge_w(p1);
        float2 f;
        f = __half22float2(*(const __half2*)&q0.x); a0 = fmaf(w0, f.x, a0); a1 = fmaf(w0, f.y, a1);
        f = __half22float2(*(const __half2*)&q0.y); a2 = fmaf(w0, f.x, a2); a3 = fmaf(w0, f.y, a3);
        f = __half22float2(*(const __half2*)&q0.z); a4 = fmaf(w0, f.x, a4); a5 = fmaf(w0, f.y, a5);
        f = __half22float2(*(const __half2*)&q0.w); a6 = fmaf(w0, f.x, a6); a7 = fmaf(w0, f.y, a7);
        f = __half22float2(*(const __half2*)&q1.x); a0 = fmaf(w1, f.x, a0); a1 = fmaf(w1, f.y, a1);
        f = __half22float2(*(const __half2*)&q1.y); a2 = fmaf(w1, f.x, a2); a3 = fmaf(w1, f.y, a3);
        f = __half22float2(*(const __half2*)&q1.z); a4 = fmaf(w1, f.x, a4); a5 = fmaf(w1, f.y, a5);
        f = __half22float2(*(const __half2*)&q1.w); a6 = fmaf(w1, f.x, a6); a7 = fmaf(w1, f.y, a7);
    }
    if (e < sp.y) {
        unsigned p = sorted[e];
        uint4 q = *(const uint4*)(t2 + (p & 0xFFFF) * 64 + fli * 8);
        float w = edge_w(p);
        float2 f;
        f = __half22float2(*(const __half2*)&q.x); a0 = fmaf(w, f.x, a0); a1 = fmaf(w, f.y, a1);
        f = __half22float2(*(const __half2*)&q.y); a2 = fmaf(w, f.x, a2); a3 = fmaf(w, f.y, a3);
        f = __half22float2(*(const __half2*)&q.z); a4 = fmaf(w, f.x, a4); a5 = fmaf(w, f.y, a5);
        f = __half22float2(*(const __half2*)&q.w); a6 = fmaf(w, f.x, a6); a7 = fmaf(w, f.y, a7);
    }
    // reduce across the 8 edge groups (lane bits 3..5)
#pragma unroll
    for (int off = 8; off < 64; off <<= 1) {
        a0 += __shfl_xor(a0, off); a1 += __shfl_xor(a1, off);
        a2 += __shfl_xor(a2, off); a3 += __shfl_xor(a3, off);
        a4 += __shfl_xor(a4, off); a5 += __shfl_xor(a5, off);
        a6 += __shfl_xor(a6, off); a7 += __shfl_xor(a7, off);
    }
    float4 bA = *(const float4*)(b2 + fli * 8);
    float4 bB = *(const float4*)(b2 + fli * 8 + 4);
    float4 wA = *(const float4*)(W3 + fli * 8);
    float4 wB = *(const float4*)(W3 + fli * 8 + 4);
    float h = fmaxf(a0 + bA.x, 0.f) * wA.x + fmaxf(a1 + bA.y, 0.f) * wA.y +
              fmaxf(a2 + bA.z, 0.f) * wA.z + fmaxf(a3 + bA.w, 0.f) * wA.w +
              fmaxf(a4 + bB.x, 0.f) * wB.x + fmaxf(a5 + bB.y, 0.f) * wB.y +
              fmaxf(a6 + bB.z, 0.f) * wB.z + fmaxf(a7 + bB.w, 0.f) * wB.w;
#pragma unroll
    for (int off = 1; off < 8; off <<= 1) h += __shfl_xor(h, off);
    if (lane == 0) t3[node] = h;
}

// ====== Layer 3: gather scalar t3 ======
__global__ void gather3(const int2* __restrict__ rowspan, const unsigned* __restrict__ sorted,
                        const float* __restrict__ t3, const float* __restrict__ b3,
                        float* __restrict__ out) {
    int i = blockIdx.x * blockDim.x + threadIdx.x;
    if (i >= N_NODES) return;
    int2 sp = rowspan[i];
    float acc = 0.f;
    for (int e = sp.x; e < sp.y; e++) {
        unsigned p = sorted[e];
        acc = fmaf(edge_w(p), t3[p & 0xFFFF], acc);
    }
    out[i] = acc + b3[0];
}

extern "C" void kernel_launch(void* const* d_in, const int* in_sizes, int n_in,
                              void* d_out, int out_size, void* d_ws, size_t ws_size,
                              hipStream_t stream) {
    const float* x  = (const float*)d_in[0];
    const int*   ei = (const int*)d_in[1];     // [2, E]
    const float* ew = (const float*)d_in[2];
    const float* W1 = (const float*)d_in[3];
    const float* b1 = (const float*)d_in[4];
    const float* W2 = (const float*)d_in[5];
    const float* b2 = (const float*)d_in[6];
    const float* W3 = (const float*)d_in[7];
    const float* b3 = (const float*)d_in[8];
    float* out = (float*)d_out;

    const int* src = ei;
    const int* dst = ei + N_EDGES;

    // workspace layout
    char* p = (char*)d_ws;
    int*  bcur    = (int*)p;            p += NBKT * sizeof(int);
    p = (char*)(((uintptr_t)p + 15) & ~(uintptr_t)15);
    int2* rowspan = (int2*)p;           p += N_NODES * sizeof(int2);            // 400 KB
    int2* binned      = (int2*)p;       p += (long)NBKT * CAP * sizeof(int2);   // 12.8 MB
    unsigned* sorted  = (unsigned*)p;   p += (long)NBKT * CAP * sizeof(unsigned); // 6.4 MB
    __half* t2    = (__half*)p;         p += 64L * N_NODES * sizeof(__half);    // 6.4 MB
    float* t3     = (float*)p;          p += N_NODES * sizeof(float);

    hipMemsetAsync(bcur, 0, NBKT * sizeof(int), stream);

    // CSR build: fixed-capacity bucket binning -> per-bucket sort
    bin_edges<<<P1_BLOCKS, 256, 0, stream>>>(src, dst, ew, bcur, binned);
    sort_bucket<<<NBKT, 256, 0, stream>>>(bcur, binned, sorted, rowspan);

    // Layer 1 (fused gather + dense 2->128 + relu + dense 128->64, fp16 out)
    fused_l1<<<(N_NODES + L1_NODES_PER_BLOCK - 1) / L1_NODES_PER_BLOCK, 256, 0, stream>>>(
        rowspan, sorted, x, W1, b1, W2, t2);

    // Layer 2 gather + fused layer-3 projection
    gather2_dot3<<<(N_NODES * 64 + 255) / 256, 256, 0, stream>>>(rowspan, sorted, t2, b2, W3, t3);

    // Layer 3
    gather3<<<(N_NODES + 255) / 256, 256, 0, stream>>>(rowspan, sorted, t3, b3, out);
}

// Round 11
// 168.542 us; speedup vs baseline: 1.1899x; 1.0165x over previous
//
#include <hip/hip_runtime.h>
#include <hip/hip_fp16.h>

#define N_NODES 50000
#define N_EDGES 800000
#define BSHIFT 8
#define NBKT ((N_NODES + 255) >> BSHIFT)                 // 196 buckets of 256 nodes
#define CAP 8192                                          // fixed bucket capacity (mean 4082, sigma 64)
#define P1_EDGES 4096
#define P1_BLOCKS ((N_EDGES + P1_EDGES - 1) / P1_EDGES)  // 196
#define SORT_LDS_CAP 6144                                 // 24+6 KB LDS staging in sort

// ===== Pass 1: bin edges into fixed-capacity bucket regions (single global pass) =====
// Stage block's edges in LDS while counting; reserve per-(block,bucket) chunk with one
// global atomic; scatter from LDS. Output: pk = src(16)|fp16w(16), dl = dst&255.
__global__ void bin_edges(const int* __restrict__ src, const int* __restrict__ dst,
                          const float* __restrict__ ew, int* __restrict__ bcur,
                          unsigned* __restrict__ bpk, unsigned char* __restrict__ bdl) {
    __shared__ unsigned spk[P1_EDGES];        // 16 KB
    __shared__ unsigned short sdst[P1_EDGES]; // 8 KB
    __shared__ int cnt[NBKT];
    __shared__ int cbase[NBKT];
    int t = threadIdx.x;
    if (t < NBKT) cnt[t] = 0;
    __syncthreads();
    int e0 = blockIdx.x * P1_EDGES;
    for (int k = 0; k < P1_EDGES / 256; k++) {
        int i = k * 256 + t;
        int e = e0 + i;
        if (e < N_EDGES) {
            int d = dst[e];
            unsigned hw = (unsigned)__half_as_ushort(__float2half(ew[e]));
            spk[i] = (unsigned)src[e] | (hw << 16);
            sdst[i] = (unsigned short)d;
            atomicAdd(&cnt[d >> BSHIFT], 1);
        }
    }
    __syncthreads();
    if (t < NBKT) {
        int v = cnt[t];
        int base = v ? atomicAdd(&bcur[t], v) : 0;
        cbase[t] = t * CAP + base;
        cnt[t] = 0;                   // reuse as local cursor
    }
    __syncthreads();
    int nmax = N_EDGES - e0;
    if (nmax > P1_EDGES) nmax = P1_EDGES;
    for (int k = 0; k < P1_EDGES / 256; k++) {
        int i = k * 256 + t;
        if (i < nmax) {
            int d = sdst[i];
            int b = d >> BSHIFT;
            int pos = cbase[b] + atomicAdd(&cnt[b], 1);
            bpk[pos] = spk[i];
            bdl[pos] = (unsigned char)(d & 255);
        }
    }
}

// ===== Pass 2: sort each bucket by exact dst (LDS-staged), emit rowspan + packed 4B edges =====
__global__ void sort_bucket(const int* __restrict__ bcur, const unsigned* __restrict__ bpk,
                            const unsigned char* __restrict__ bdl,
                            unsigned* __restrict__ sorted, int2* __restrict__ rowspan) {
    __shared__ unsigned spk[SORT_LDS_CAP];       // 24 KB
    __shared__ unsigned char sdl[SORT_LDS_CAP];  // 6 KB
    __shared__ int nh[256];
    __shared__ int scn[256];
    __shared__ int lcur[256];
    int b = blockIdx.x;
    int t = threadIdx.x;
    int base = b * CAP;
    int n = bcur[b];
    if (n > CAP) n = CAP;                // unreachable with 60-sigma headroom; safety only
    bool lds_path = (n <= SORT_LDS_CAP);
    nh[t] = 0;
    __syncthreads();
    if (lds_path) {
        for (int e = t; e < n; e += 256) {
            spk[e] = bpk[base + e];
            unsigned char d = bdl[base + e];
            sdl[e] = d;
            atomicAdd(&nh[d], 1);
        }
    } else {
        for (int e = t; e < n; e += 256)
            atomicAdd(&nh[bdl[base + e]], 1);
    }
    __syncthreads();
    int v = nh[t];
    scn[t] = v;
    __syncthreads();
    for (int off = 1; off < 256; off <<= 1) {
        int u = (t >= off) ? scn[t - off] : 0;
        __syncthreads();
        scn[t] += u;
        __syncthreads();
    }
    int ex = scn[t] - v;
    int node = (b << BSHIFT) + t;
    if (node < N_NODES) rowspan[node] = make_int2(base + ex, base + ex + v);
    __syncthreads();
    nh[t] = ex;
    lcur[t] = 0;
    __syncthreads();
    if (lds_path) {
        for (int e = t; e < n; e += 256) {
            int dlow = sdl[e];
            int pos = base + nh[dlow] + atomicAdd(&lcur[dlow], 1);
            sorted[pos] = spk[e];
        }
    } else {
        for (int e = t; e < n; e += 256) {
            int dlow = bdl[base + e];
            int pos = base + nh[dlow] + atomicAdd(&lcur[dlow], 1);
            sorted[pos] = bpk[base + e];
        }
    }
}

__device__ __forceinline__ float edge_w(unsigned p) {
    return __half2float(__ushort_as_half((unsigned short)(p >> 16)));
}

// ====== Fused layer 1: gather x -> h1 = relu(.@W1+b1) -> t2 = h1 @ W2 (fp16 [node][64]) ======
#define L1_NPW 2
#define L1_NODES_PER_BLOCK (4 * 4 * L1_NPW)  // 32
__global__ void fused_l1(const int2* __restrict__ rowspan, const unsigned* __restrict__ sorted,
                         const float* __restrict__ x, const float* __restrict__ W1,
                         const float* __restrict__ b1, const float* __restrict__ W2,
                         __half* __restrict__ t2) {
    __shared__ float w2s[128 * 64];
    __shared__ float hls[4][4][128];
    for (int k = threadIdx.x; k < 128 * 64; k += 256) w2s[k] = W2[k];
    int wave = threadIdx.x >> 6;
    int lane = threadIdx.x & 63;
    float w1a = W1[lane],      w1b = W1[128 + lane];
    float w1c = W1[64 + lane], w1d = W1[192 + lane];
    float b1lo = b1[lane], b1hi = b1[64 + lane];
    __syncthreads();

    int sub = lane >> 4;
    int sl  = lane & 15;

    for (int it = 0; it < L1_NPW; it++) {
        int base = blockIdx.x * L1_NODES_PER_BLOCK + wave * (4 * L1_NPW) + it * 4;
        int gnode = base + sub;
        float a0 = 0.f, a1 = 0.f;
        if (gnode < N_NODES) {
            int2 sp = rowspan[gnode];
            for (int e = sp.x + sl; e < sp.y; e += 16) {
                unsigned p = sorted[e];
                float w = edge_w(p);
                float2 xv = ((const float2*)x)[p & 0xFFFF];
                a0 = fmaf(w, xv.x, a0);
                a1 = fmaf(w, xv.y, a1);
            }
        }
#pragma unroll
        for (int off = 1; off < 16; off <<= 1) {
            a0 += __shfl_xor(a0, off);
            a1 += __shfl_xor(a1, off);
        }
#pragma unroll
        for (int n = 0; n < 4; n++) {
            float an0 = __shfl(a0, 16 * n);
            float an1 = __shfl(a1, 16 * n);
            float hlo = fmaxf(fmaf(an0, w1a, fmaf(an1, w1b, b1lo)), 0.f);
            float hhi = fmaxf(fmaf(an0, w1c, fmaf(an1, w1d, b1hi)), 0.f);
            hls[wave][n][lane] = hlo;
            hls[wave][n][64 + lane] = hhi;
        }
        float acc0 = 0.f, acc1 = 0.f, acc2 = 0.f, acc3 = 0.f;
#pragma unroll 4
        for (int k4 = 0; k4 < 32; k4++) {
            float w0 = w2s[(4 * k4 + 0) * 64 + lane];
            float w1 = w2s[(4 * k4 + 1) * 64 + lane];
            float w2 = w2s[(4 * k4 + 2) * 64 + lane];
            float w3 = w2s[(4 * k4 + 3) * 64 + lane];
            float4 h0 = *(const float4*)&hls[wave][0][4 * k4];
            float4 h1 = *(const float4*)&hls[wave][1][4 * k4];
            float4 h2 = *(const float4*)&hls[wave][2][4 * k4];
            float4 h3 = *(const float4*)&hls[wave][3][4 * k4];
            acc0 = fmaf(h0.x, w0, fmaf(h0.y, w1, fmaf(h0.z, w2, fmaf(h0.w, w3, acc0))));
            acc1 = fmaf(h1.x, w0, fmaf(h1.y, w1, fmaf(h1.z, w2, fmaf(h1.w, w3, acc1))));
            acc2 = fmaf(h2.x, w0, fmaf(h2.y, w1, fmaf(h2.z, w2, fmaf(h2.w, w3, acc2))));
            acc3 = fmaf(h3.x, w0, fmaf(h3.y, w1, fmaf(h3.z, w2, fmaf(h3.w, w3, acc3))));
        }
        if (base + 0 < N_NODES) t2[(base + 0) * 64 + lane] = __float2half(acc0);
        if (base + 1 < N_NODES) t2[(base + 1) * 64 + lane] = __float2half(acc1);
        if (base + 2 < N_NODES) t2[(base + 2) * 64 + lane] = __float2half(acc2);
        if (base + 3 < N_NODES) t2[(base + 3) * 64 + lane] = __float2half(acc3);
    }
}

// ====== Layer 2 gather: wave per node, 8 edges per load instruction ======
__global__ void gather2_dot3(const int2* __restrict__ rowspan, const unsigned* __restrict__ sorted,
                             const __half* __restrict__ t2, const float* __restrict__ b2,
                             const float* __restrict__ W3, float* __restrict__ t3) {
    int gtid = blockIdx.x * blockDim.x + threadIdx.x;
    int node = gtid >> 6;
    int lane = threadIdx.x & 63;
    if (node >= N_NODES) return;
    int eg  = lane >> 3;
    int fli = lane & 7;
    int2 sp = rowspan[node];
    float a0 = 0.f, a1 = 0.f, a2 = 0.f, a3 = 0.f, a4 = 0.f, a5 = 0.f, a6 = 0.f, a7 = 0.f;
    int e = sp.x + eg;
    for (; e + 8 < sp.y; e += 16) {
        unsigned p0 = sorted[e];
        unsigned p1 = sorted[e + 8];
        uint4 q0 = *(const uint4*)(t2 + (p0 & 0xFFFF) * 64 + fli * 8);
        uint4 q1 = *(const uint4*)(t2 + (p1 & 0xFFFF) * 64 + fli * 8);
        float w0 = edge_w(p0), w1 = edge_w(p1);
        float2 f;
        f = __half22float2(*(const __half2*)&q0.x); a0 = fmaf(w0, f.x, a0); a1 = fmaf(w0, f.y, a1);
        f = __half22float2(*(const __half2*)&q0.y); a2 = fmaf(w0, f.x, a2); a3 = fmaf(w0, f.y, a3);
        f = __half22float2(*(const __half2*)&q0.z); a4 = fmaf(w0, f.x, a4); a5 = fmaf(w0, f.y, a5);
        f = __half22float2(*(const __half2*)&q0.w); a6 = fmaf(w0, f.x, a6); a7 = fmaf(w0, f.y, a7);
        f = __half22float2(*(const __half2*)&q1.x); a0 = fmaf(w1, f.x, a0); a1 = fmaf(w1, f.y, a1);
        f = __half22float2(*(const __half2*)&q1.y); a2 = fmaf(w1, f.x, a2); a3 = fmaf(w1, f.y, a3);
        f = __half22float2(*(const __half2*)&q1.z); a4 = fmaf(w1, f.x, a4); a5 = fmaf(w1, f.y, a5);
        f = __half22float2(*(const __half2*)&q1.w); a6 = fmaf(w1, f.x, a6); a7 = fmaf(w1, f.y, a7);
    }
    if (e < sp.y) {
        unsigned p = sorted[e];
        uint4 q = *(const uint4*)(t2 + (p & 0xFFFF) * 64 + fli * 8);
        float w = edge_w(p);
        float2 f;
        f = __half22float2(*(const __half2*)&q.x); a0 = fmaf(w, f.x, a0); a1 = fmaf(w, f.y, a1);
        f = __half22float2(*(const __half2*)&q.y); a2 = fmaf(w, f.x, a2); a3 = fmaf(w, f.y, a3);
        f = __half22float2(*(const __half2*)&q.z); a4 = fmaf(w, f.x, a4); a5 = fmaf(w, f.y, a5);
        f = __half22float2(*(const __half2*)&q.w); a6 = fmaf(w, f.x, a6); a7 = fmaf(w, f.y, a7);
    }
#pragma unroll
    for (int off = 8; off < 64; off <<= 1) {
        a0 += __shfl_xor(a0, off); a1 += __shfl_xor(a1, off);
        a2 += __shfl_xor(a2, off); a3 += __shfl_xor(a3, off);
        a4 += __shfl_xor(a4, off); a5 += __shfl_xor(a5, off);
        a6 += __shfl_xor(a6, off); a7 += __shfl_xor(a7, off);
    }
    float4 bA = *(const float4*)(b2 + fli * 8);
    float4 bB = *(const float4*)(b2 + fli * 8 + 4);
    float4 wA = *(const float4*)(W3 + fli * 8);
    float4 wB = *(const float4*)(W3 + fli * 8 + 4);
    float h = fmaxf(a0 + bA.x, 0.f) * wA.x + fmaxf(a1 + bA.y, 0.f) * wA.y +
              fmaxf(a2 + bA.z, 0.f) * wA.z + fmaxf(a3 + bA.w, 0.f) * wA.w +
              fmaxf(a4 + bB.x, 0.f) * wB.x + fmaxf(a5 + bB.y, 0.f) * wB.y +
              fmaxf(a6 + bB.z, 0.f) * wB.z + fmaxf(a7 + bB.w, 0.f) * wB.w;
#pragma unroll
    for (int off = 1; off < 8; off <<= 1) h += __shfl_xor(h, off);
    if (lane == 0) t3[node] = h;
}

// ====== Layer 3: gather scalar t3, 16 lanes/node (wave per 4 nodes) ======
__global__ void gather3(const int2* __restrict__ rowspan, const unsigned* __restrict__ sorted,
                        const float* __restrict__ t3, const float* __restrict__ b3,
                        float* __restrict__ out) {
    int gtid = blockIdx.x * blockDim.x + threadIdx.x;
    int wid = gtid >> 6;
    int lane = threadIdx.x & 63;
    int sub = lane >> 4;
    int sl  = lane & 15;
    int node = wid * 4 + sub;
    if (node >= N_NODES) return;
    int2 sp = rowspan[node];
    float acc = 0.f;
    for (int e = sp.x + sl; e < sp.y; e += 16) {
        unsigned p = sorted[e];
        acc = fmaf(edge_w(p), t3[p & 0xFFFF], acc);
    }
#pragma unroll
    for (int off = 1; off < 16; off <<= 1) acc += __shfl_xor(acc, off);
    if (sl == 0) out[node] = acc + b3[0];
}

extern "C" void kernel_launch(void* const* d_in, const int* in_sizes, int n_in,
                              void* d_out, int out_size, void* d_ws, size_t ws_size,
                              hipStream_t stream) {
    const float* x  = (const float*)d_in[0];
    const int*   ei = (const int*)d_in[1];     // [2, E]
    const float* ew = (const float*)d_in[2];
    const float* W1 = (const float*)d_in[3];
    const float* b1 = (const float*)d_in[4];
    const float* W2 = (const float*)d_in[5];
    const float* b2 = (const float*)d_in[6];
    const float* W3 = (const float*)d_in[7];
    const float* b3 = (const float*)d_in[8];
    float* out = (float*)d_out;

    const int* src = ei;
    const int* dst = ei + N_EDGES;

    // workspace layout
    char* p = (char*)d_ws;
    int*  bcur    = (int*)p;            p += NBKT * sizeof(int);
    p = (char*)(((uintptr_t)p + 15) & ~(uintptr_t)15);
    int2* rowspan = (int2*)p;           p += N_NODES * sizeof(int2);              // 400 KB
    unsigned* bpk = (unsigned*)p;       p += (long)NBKT * CAP * sizeof(unsigned); // 6.4 MB
    unsigned char* bdl = (unsigned char*)p; p += (long)NBKT * CAP;                // 1.6 MB
    p = (char*)(((uintptr_t)p + 15) & ~(uintptr_t)15);
    unsigned* sorted  = (unsigned*)p;   p += (long)NBKT * CAP * sizeof(unsigned); // 6.4 MB
    __half* t2    = (__half*)p;         p += 64L * N_NODES * sizeof(__half);      // 6.4 MB
    float* t3     = (float*)p;          p += N_NODES * sizeof(float);

    hipMemsetAsync(bcur, 0, NBKT * sizeof(int), stream);

    // CSR build: single-pass binning -> per-bucket sort
    bin_edges<<<P1_BLOCKS, 256, 0, stream>>>(src, dst, ew, bcur, bpk, bdl);
    sort_bucket<<<NBKT, 256, 0, stream>>>(bcur, bpk, bdl, sorted, rowspan);

    // Layer 1 (fused gather + dense 2->128 + relu + dense 128->64, fp16 out)
    fused_l1<<<(N_NODES + L1_NODES_PER_BLOCK - 1) / L1_NODES_PER_BLOCK, 256, 0, stream>>>(
        rowspan, sorted, x, W1, b1, W2, t2);

    // Layer 2 gather + fused layer-3 projection
    gather2_dot3<<<(N_NODES * 64 + 255) / 256, 256, 0, stream>>>(rowspan, sorted, t2, b2, W3, t3);

    // Layer 3 (16 lanes/node)
    gather3<<<((N_NODES + 3) / 4 * 64 + 255) / 256, 256, 0, stream>>>(rowspan, sorted, t3, b3, out);
}

// Round 12
// 160.358 us; speedup vs baseline: 1.2507x; 1.0510x over previous
//
#include <hip/hip_runtime.h>
#include <hip/hip_fp16.h>

#define N_NODES 50000
#define N_EDGES 800000
#define BSHIFT 8
#define NBKT ((N_NODES + 255) >> BSHIFT)                 // 196 buckets of 256 nodes
#define CAP 8192                                          // fixed bucket capacity (mean 4082, sigma 64)
#define P1_EDGES 4096
#define P1_BLOCKS ((N_EDGES + P1_EDGES - 1) / P1_EDGES)  // 196
#define BIN_THREADS 1024
#define SORT_THREADS 512
#define SORT_LDS_CAP 6144                                 // 24+6 KB LDS staging in sort

// ===== Pass 1: bin edges into fixed-capacity bucket regions (single global pass, 1024 thr) =====
__global__ void bin_edges(const int* __restrict__ src, const int* __restrict__ dst,
                          const float* __restrict__ ew, int* __restrict__ bcur,
                          unsigned* __restrict__ bpk, unsigned char* __restrict__ bdl) {
    __shared__ unsigned spk[P1_EDGES];        // 16 KB
    __shared__ unsigned short sdst[P1_EDGES]; // 8 KB
    __shared__ int cnt[NBKT];
    __shared__ int cbase[NBKT];
    int t = threadIdx.x;
    if (t < NBKT) cnt[t] = 0;
    __syncthreads();
    int e0 = blockIdx.x * P1_EDGES;
    for (int k = 0; k < P1_EDGES / BIN_THREADS; k++) {
        int i = k * BIN_THREADS + t;
        int e = e0 + i;
        if (e < N_EDGES) {
            int d = dst[e];
            unsigned hw = (unsigned)__half_as_ushort(__float2half(ew[e]));
            spk[i] = (unsigned)src[e] | (hw << 16);
            sdst[i] = (unsigned short)d;
            atomicAdd(&cnt[d >> BSHIFT], 1);
        }
    }
    __syncthreads();
    if (t < NBKT) {
        int v = cnt[t];
        int base = v ? atomicAdd(&bcur[t], v) : 0;
        cbase[t] = t * CAP + base;
        cnt[t] = 0;                   // reuse as local cursor
    }
    __syncthreads();
    int nmax = N_EDGES - e0;
    if (nmax > P1_EDGES) nmax = P1_EDGES;
    for (int k = 0; k < P1_EDGES / BIN_THREADS; k++) {
        int i = k * BIN_THREADS + t;
        if (i < nmax) {
            int d = sdst[i];
            int b = d >> BSHIFT;
            int pos = cbase[b] + atomicAdd(&cnt[b], 1);
            bpk[pos] = spk[i];
            bdl[pos] = (unsigned char)(d & 255);
        }
    }
}

// ===== Pass 2: sort each bucket by exact dst (LDS-staged, 512 thr), emit rowspan + 4B edges =====
__global__ void sort_bucket(const int* __restrict__ bcur, const unsigned* __restrict__ bpk,
                            const unsigned char* __restrict__ bdl,
                            unsigned* __restrict__ sorted, int2* __restrict__ rowspan) {
    __shared__ unsigned spk[SORT_LDS_CAP];       // 24 KB
    __shared__ unsigned char sdl[SORT_LDS_CAP];  // 6 KB
    __shared__ int nh[256];
    __shared__ int scn[256];
    __shared__ int lcur[256];
    int b = blockIdx.x;
    int t = threadIdx.x;
    int base = b * CAP;
    int n = bcur[b];
    if (n > CAP) n = CAP;                // unreachable with 60-sigma headroom; safety only
    bool lds_path = (n <= SORT_LDS_CAP);
    if (t < 256) nh[t] = 0;
    __syncthreads();
    if (lds_path) {
        for (int e = t; e < n; e += SORT_THREADS) {
            spk[e] = bpk[base + e];
            unsigned char d = bdl[base + e];
            sdl[e] = d;
            atomicAdd(&nh[d], 1);
        }
    } else {
        for (int e = t; e < n; e += SORT_THREADS)
            atomicAdd(&nh[bdl[base + e]], 1);
    }
    __syncthreads();
    int v = 0;
    if (t < 256) { v = nh[t]; scn[t] = v; }
    __syncthreads();
    for (int off = 1; off < 256; off <<= 1) {
        int u = (t < 256 && t >= off) ? scn[t - off] : 0;
        __syncthreads();
        if (t < 256) scn[t] += u;
        __syncthreads();
    }
    if (t < 256) {
        int ex = scn[t] - v;
        int node = (b << BSHIFT) + t;
        if (node < N_NODES) rowspan[node] = make_int2(base + ex, base + ex + v);
        nh[t] = ex;
        lcur[t] = 0;
    }
    __syncthreads();
    if (lds_path) {
        for (int e = t; e < n; e += SORT_THREADS) {
            int dlow = sdl[e];
            int pos = base + nh[dlow] + atomicAdd(&lcur[dlow], 1);
            sorted[pos] = spk[e];
        }
    } else {
        for (int e = t; e < n; e += SORT_THREADS) {
            int dlow = bdl[base + e];
            int pos = base + nh[dlow] + atomicAdd(&lcur[dlow], 1);
            sorted[pos] = bpk[base + e];
        }
    }
}

__device__ __forceinline__ float edge_w(unsigned p) {
    return __half2float(__ushort_as_half((unsigned short)(p >> 16)));
}

// ====== Fused layer 1: gather x -> h1 = relu(.@W1+b1) -> t2 = h1 @ W2 (fp16 [node][64]) ======
// Wave handles 8 nodes: two 4-node gather sub-passes fill hls[wave][8][128], then ONE
// dense pass with 8 accumulators shares each w2s read across 8 nodes.
#define L1_NODES_PER_BLOCK 32   // 4 waves * 8 nodes
__global__ void fused_l1(const int2* __restrict__ rowspan, const unsigned* __restrict__ sorted,
                         const float* __restrict__ x, const float* __restrict__ W1,
                         const float* __restrict__ b1, const float* __restrict__ W2,
                         __half* __restrict__ t2) {
    __shared__ float w2s[128 * 64];      // 32 KB
    __shared__ float hls[4][8][128];     // 16 KB
    for (int k = threadIdx.x; k < 128 * 64; k += 256) w2s[k] = W2[k];
    int wave = threadIdx.x >> 6;
    int lane = threadIdx.x & 63;
    float w1a = W1[lane],      w1b = W1[128 + lane];
    float w1c = W1[64 + lane], w1d = W1[192 + lane];
    float b1lo = b1[lane], b1hi = b1[64 + lane];
    __syncthreads();

    int sub = lane >> 4;
    int sl  = lane & 15;
    int base = blockIdx.x * L1_NODES_PER_BLOCK + wave * 8;

    // ---- gather phase: two sub-passes of 4 nodes, 16 lanes each ----
#pragma unroll
    for (int g = 0; g < 2; g++) {
        int gnode = base + g * 4 + sub;
        float a0 = 0.f, a1 = 0.f;
        if (gnode < N_NODES) {
            int2 sp = rowspan[gnode];
            for (int e = sp.x + sl; e < sp.y; e += 16) {
                unsigned p = sorted[e];
                float w = edge_w(p);
                float2 xv = ((const float2*)x)[p & 0xFFFF];
                a0 = fmaf(w, xv.x, a0);
                a1 = fmaf(w, xv.y, a1);
            }
        }
#pragma unroll
        for (int off = 1; off < 16; off <<= 1) {
            a0 += __shfl_xor(a0, off);
            a1 += __shfl_xor(a1, off);
        }
#pragma unroll
        for (int n = 0; n < 4; n++) {
            float an0 = __shfl(a0, 16 * n);
            float an1 = __shfl(a1, 16 * n);
            float hlo = fmaxf(fmaf(an0, w1a, fmaf(an1, w1b, b1lo)), 0.f);
            float hhi = fmaxf(fmaf(an0, w1c, fmaf(an1, w1d, b1hi)), 0.f);
            hls[wave][g * 4 + n][lane] = hlo;
            hls[wave][g * 4 + n][64 + lane] = hhi;
        }
    }
    // ---- dense phase: 8 nodes share each w2s read ----
    float acc[8] = {0.f, 0.f, 0.f, 0.f, 0.f, 0.f, 0.f, 0.f};
#pragma unroll 2
    for (int k4 = 0; k4 < 32; k4++) {
        float w0 = w2s[(4 * k4 + 0) * 64 + lane];
        float w1 = w2s[(4 * k4 + 1) * 64 + lane];
        float w2 = w2s[(4 * k4 + 2) * 64 + lane];
        float w3 = w2s[(4 * k4 + 3) * 64 + lane];
#pragma unroll
        for (int n = 0; n < 8; n++) {
            float4 h = *(const float4*)&hls[wave][n][4 * k4];
            acc[n] = fmaf(h.x, w0, fmaf(h.y, w1, fmaf(h.z, w2, fmaf(h.w, w3, acc[n]))));
        }
    }
#pragma unroll
    for (int n = 0; n < 8; n++)
        if (base + n < N_NODES) t2[(base + n) * 64 + lane] = __float2half(acc[n]);
}

// ====== Layer 2 gather: wave per node, 8 edges per load instruction ======
__global__ void gather2_dot3(const int2* __restrict__ rowspan, const unsigned* __restrict__ sorted,
                             const __half* __restrict__ t2, const float* __restrict__ b2,
                             const float* __restrict__ W3, float* __restrict__ t3) {
    int gtid = blockIdx.x * blockDim.x + threadIdx.x;
    int node = gtid >> 6;
    int lane = threadIdx.x & 63;
    if (node >= N_NODES) return;
    int eg  = lane >> 3;
    int fli = lane & 7;
    int2 sp = rowspan[node];
    float a0 = 0.f, a1 = 0.f, a2 = 0.f, a3 = 0.f, a4 = 0.f, a5 = 0.f, a6 = 0.f, a7 = 0.f;
    int e = sp.x + eg;
    for (; e + 8 < sp.y; e += 16) {
        unsigned p0 = sorted[e];
        unsigned p1 = sorted[e + 8];
        uint4 q0 = *(const uint4*)(t2 + (p0 & 0xFFFF) * 64 + fli * 8);
        uint4 q1 = *(const uint4*)(t2 + (p1 & 0xFFFF) * 64 + fli * 8);
        float w0 = edge_w(p0), w1 = edge_w(p1);
        float2 f;
        f = __half22float2(*(const __half2*)&q0.x); a0 = fmaf(w0, f.x, a0); a1 = fmaf(w0, f.y, a1);
        f = __half22float2(*(const __half2*)&q0.y); a2 = fmaf(w0, f.x, a2); a3 = fmaf(w0, f.y, a3);
        f = __half22float2(*(const __half2*)&q0.z); a4 = fmaf(w0, f.x, a4); a5 = fmaf(w0, f.y, a5);
        f = __half22float2(*(const __half2*)&q0.w); a6 = fmaf(w0, f.x, a6); a7 = fmaf(w0, f.y, a7);
        f = __half22float2(*(const __half2*)&q1.x); a0 = fmaf(w1, f.x, a0); a1 = fmaf(w1, f.y, a1);
        f = __half22float2(*(const __half2*)&q1.y); a2 = fmaf(w1, f.x, a2); a3 = fmaf(w1, f.y, a3);
        f = __half22float2(*(const __half2*)&q1.z); a4 = fmaf(w1, f.x, a4); a5 = fmaf(w1, f.y, a5);
        f = __half22float2(*(const __half2*)&q1.w); a6 = fmaf(w1, f.x, a6); a7 = fmaf(w1, f.y, a7);
    }
    if (e < sp.y) {
        unsigned p = sorted[e];
        uint4 q = *(const uint4*)(t2 + (p & 0xFFFF) * 64 + fli * 8);
        float w = edge_w(p);
        float2 f;
        f = __half22float2(*(const __half2*)&q.x); a0 = fmaf(w, f.x, a0); a1 = fmaf(w, f.y, a1);
        f = __half22float2(*(const __half2*)&q.y); a2 = fmaf(w, f.x, a2); a3 = fmaf(w, f.y, a3);
        f = __half22float2(*(const __half2*)&q.z); a4 = fmaf(w, f.x, a4); a5 = fmaf(w, f.y, a5);
        f = __half22float2(*(const __half2*)&q.w); a6 = fmaf(w, f.x, a6); a7 = fmaf(w, f.y, a7);
    }
#pragma unroll
    for (int off = 8; off < 64; off <<= 1) {
        a0 += __shfl_xor(a0, off); a1 += __shfl_xor(a1, off);
        a2 += __shfl_xor(a2, off); a3 += __shfl_xor(a3, off);
        a4 += __shfl_xor(a4, off); a5 += __shfl_xor(a5, off);
        a6 += __shfl_xor(a6, off); a7 += __shfl_xor(a7, off);
    }
    float4 bA = *(const float4*)(b2 + fli * 8);
    float4 bB = *(const float4*)(b2 + fli * 8 + 4);
    float4 wA = *(const float4*)(W3 + fli * 8);
    float4 wB = *(const float4*)(W3 + fli * 8 + 4);
    float h = fmaxf(a0 + bA.x, 0.f) * wA.x + fmaxf(a1 + bA.y, 0.f) * wA.y +
              fmaxf(a2 + bA.z, 0.f) * wA.z + fmaxf(a3 + bA.w, 0.f) * wA.w +
              fmaxf(a4 + bB.x, 0.f) * wB.x + fmaxf(a5 + bB.y, 0.f) * wB.y +
              fmaxf(a6 + bB.z, 0.f) * wB.z + fmaxf(a7 + bB.w, 0.f) * wB.w;
#pragma unroll
    for (int off = 1; off < 8; off <<= 1) h += __shfl_xor(h, off);
    if (lane == 0) t3[node] = h;
}

// ====== Layer 3: gather scalar t3, 16 lanes/node (wave per 4 nodes) ======
__global__ void gather3(const int2* __restrict__ rowspan, const unsigned* __restrict__ sorted,
                        const float* __restrict__ t3, const float* __restrict__ b3,
                        float* __restrict__ out) {
    int gtid = blockIdx.x * blockDim.x + threadIdx.x;
    int wid = gtid >> 6;
    int lane = threadIdx.x & 63;
    int sub = lane >> 4;
    int sl  = lane & 15;
    int node = wid * 4 + sub;
    if (node >= N_NODES) return;
    int2 sp = rowspan[node];
    float acc = 0.f;
    for (int e = sp.x + sl; e < sp.y; e += 16) {
        unsigned p = sorted[e];
        acc = fmaf(edge_w(p), t3[p & 0xFFFF], acc);
    }
#pragma unroll
    for (int off = 1; off < 16; off <<= 1) acc += __shfl_xor(acc, off);
    if (sl == 0) out[node] = acc + b3[0];
}

extern "C" void kernel_launch(void* const* d_in, const int* in_sizes, int n_in,
                              void* d_out, int out_size, void* d_ws, size_t ws_size,
                              hipStream_t stream) {
    const float* x  = (const float*)d_in[0];
    const int*   ei = (const int*)d_in[1];     // [2, E]
    const float* ew = (const float*)d_in[2];
    const float* W1 = (const float*)d_in[3];
    const float* b1 = (const float*)d_in[4];
    const float* W2 = (const float*)d_in[5];
    const float* b2 = (const float*)d_in[6];
    const float* W3 = (const float*)d_in[7];
    const float* b3 = (const float*)d_in[8];
    float* out = (float*)d_out;

    const int* src = ei;
    const int* dst = ei + N_EDGES;

    // workspace layout
    char* p = (char*)d_ws;
    int*  bcur    = (int*)p;            p += NBKT * sizeof(int);
    p = (char*)(((uintptr_t)p + 15) & ~(uintptr_t)15);
    int2* rowspan = (int2*)p;           p += N_NODES * sizeof(int2);              // 400 KB
    unsigned* bpk = (unsigned*)p;       p += (long)NBKT * CAP * sizeof(unsigned); // 6.4 MB
    unsigned char* bdl = (unsigned char*)p; p += (long)NBKT * CAP;                // 1.6 MB
    p = (char*)(((uintptr_t)p + 15) & ~(uintptr_t)15);
    unsigned* sorted  = (unsigned*)p;   p += (long)NBKT * CAP * sizeof(unsigned); // 6.4 MB
    __half* t2    = (__half*)p;         p += 64L * N_NODES * sizeof(__half);      // 6.4 MB
    float* t3     = (float*)p;          p += N_NODES * sizeof(float);

    hipMemsetAsync(bcur, 0, NBKT * sizeof(int), stream);

    // CSR build: single-pass binning -> per-bucket sort
    bin_edges<<<P1_BLOCKS, BIN_THREADS, 0, stream>>>(src, dst, ew, bcur, bpk, bdl);
    sort_bucket<<<NBKT, SORT_THREADS, 0, stream>>>(bcur, bpk, bdl, sorted, rowspan);

    // Layer 1 (fused gather + dense 2->128 + relu + dense 128->64, fp16 out)
    fused_l1<<<(N_NODES + L1_NODES_PER_BLOCK - 1) / L1_NODES_PER_BLOCK, 256, 0, stream>>>(
        rowspan, sorted, x, W1, b1, W2, t2);

    // Layer 2 gather + fused layer-3 projection
    gather2_dot3<<<(N_NODES * 64 + 255) / 256, 256, 0, stream>>>(rowspan, sorted, t2, b2, W3, t3);

    // Layer 3 (16 lanes/node)
    gather3<<<((N_NODES + 3) / 4 * 64 + 255) / 256, 256, 0, stream>>>(rowspan, sorted, t3, b3, out);
}